// Round 10
// baseline (333.628 us; speedup 1.0000x reference)
//
#include <hip/hip_runtime.h>
#include <hip/hip_cooperative_groups.h>
#include <math.h>

namespace cg = cooperative_groups;

#define N_PTS 16384
#define M_TGT 16384
#define TPN 8192
#define DUB2 4.0f
#define BMASK_WORDS (4*64*64*64/32)
#define CAP 8192
#define NBLK 512
#define INFF 3.4e38f

__device__ __forceinline__ unsigned int mono_key(float f) {
    unsigned int u = __float_as_uint(f);
    return (u & 0x80000000u) ? ~u : (u | 0x80000000u);
}

// One cooperative kernel, 512 blocks x 256 threads (2 blocks/CU, ~27KB LDS, VGPR<=128):
// A: zero bmask/cnt + GEMM (32 rows/block) | sync
// B: block 0 = radix-select (ballot-dedup pass0) ; blocks 1..128 = scatter | sync
// D: NN, 4 jslice-waves per 64-point group, uniform-addr float4 loads | sync
// E: epilogue
__global__ __launch_bounds__(256, 4) void k_all(
    const float* __restrict__ fea, const float* __restrict__ Wup,
    const float* __restrict__ Wcls, const int* __restrict__ coords,
    const int* __restrict__ tcoords,
    float* __restrict__ out_pred, float* __restrict__ out_fea,
    float* __restrict__ out_keep, float* __restrict__ out_kt,
    float* __restrict__ out_loss,
    int* __restrict__ cnt, unsigned int* __restrict__ bmask,
    float* __restrict__ thres_p, float4* __restrict__ tgt4,
    float4* __restrict__ pt4, int* __restrict__ porig,
    float* __restrict__ partial)
{
    __shared__ float Ws[64*64];
    __shared__ float fs[16*68];
    __shared__ unsigned int whist[4][256];
    __shared__ unsigned int hist[256], scanb[256];
    __shared__ unsigned int sh_prefix, sh_rank;
    __shared__ float kscale[32];

    cg::grid_group grid = cg::this_grid();
    const int tid = threadIdx.x;
    const int blk = blockIdx.x;
    const int lane = tid & 63;

    // ---------------- Phase A: zeroing + GEMM ----------------
    if (tid < 64) bmask[blk*64 + tid] = 0u;                 // 512*64 = 32768 words
    if (blk == 0 && tid >= 64 && tid < 72) cnt[tid-64] = 0;

    for (int t = tid; t < 1024; t += 256)
        ((float4*)Ws)[t] = ((const float4*)Wup)[t];
    float4 wc = *(const float4*)&Wcls[(tid & 15) * 4];

    for (int g = 0; g < 2; ++g) {
        const int r0 = blk*32 + g*16;
        __syncthreads();
        {
            float4 v = ((const float4*)(fea + r0*64))[tid];
            int r = tid >> 4, c = (tid & 15) * 4;
            fs[r*68+c+0]=v.x; fs[r*68+c+1]=v.y; fs[r*68+c+2]=v.z; fs[r*68+c+3]=v.w;
        }
        __syncthreads();
        const int cg4 = tid & 15, r = tid >> 4;
        float a0=0.f,a1=0.f,a2=0.f,a3=0.f;
        const float* fr = fs + r*68;
        #pragma unroll
        for (int k = 0; k < 64; ++k) {
            float f = fr[k];
            float4 w = *(const float4*)&Ws[k*64 + cg4*4];
            a0=fmaf(f,w.x,a0); a1=fmaf(f,w.y,a1); a2=fmaf(f,w.z,a2); a3=fmaf(f,w.w,a3);
        }
        a0=fmaxf(a0,0.f); a1=fmaxf(a1,0.f); a2=fmaxf(a2,0.f); a3=fmaxf(a3,0.f);
        const int row = r0 + r;
        *(float4*)&out_fea[row*64 + cg4*4] = make_float4(a0,a1,a2,a3);
        float s = a0*wc.x + a1*wc.y + a2*wc.z + a3*wc.w;
        for (int off = 1; off < 16; off <<= 1) s += __shfl_xor(s, off, 16);
        if (cg4 == 0) out_pred[row] = s;
    }

    grid.sync();

    // ---------------- Phase B: select (block 0) || scatter (blocks 1..128) ----------------
    if (blk == 0) {
        const int wv = tid >> 6;
        if (tid == 0) { sh_prefix = 0u; sh_rank = TPN - 1; }
        for (int pass = 0; pass < 4; ++pass) {
            const int shift = 24 - pass*8;
            for (int t = tid; t < 1024; t += 256) ((unsigned int*)whist)[t] = 0u;
            __syncthreads();
            const unsigned int prefix = sh_prefix;
            const unsigned int rank = sh_rank;
            for (int i = tid; i < N_PTS; i += 256) {
                unsigned int u = mono_key(out_pred[i]);
                unsigned int bin = (u >> shift) & 255u;
                if (pass == 0) {
                    // ballot-dedup: keys cluster in few exponent bins -> few iterations,
                    // one LDS atomic per distinct bin per wave (kills 64-way RMW serial)
                    unsigned long long todo = ~0ull;
                    while (todo) {
                        int L = __ffsll(todo) - 1;
                        unsigned int bL = __shfl(bin, L);
                        unsigned long long m = __ballot(bin == bL);
                        if (lane == L) atomicAdd(&whist[wv][bL], (unsigned int)__popcll(m));
                        todo &= ~m;
                    }
                } else {
                    if ((u >> (shift+8)) == prefix) atomicAdd(&whist[wv][bin], 1u);
                }
            }
            __syncthreads();
            {
                unsigned int s = whist[0][tid] + whist[1][tid] + whist[2][tid] + whist[3][tid];
                hist[tid] = s; scanb[tid] = s;
            }
            __syncthreads();
            for (int d = 1; d < 256; d <<= 1) {
                unsigned int v = (tid >= d) ? scanb[tid-d] : 0u;
                __syncthreads();
                scanb[tid] += v;
                __syncthreads();
            }
            {
                unsigned int hi = scanb[tid], lo = hi - hist[tid];
                if (rank >= lo && rank < hi) { sh_prefix = (prefix<<8)|(unsigned int)tid; sh_rank = rank-lo; }
            }
            __syncthreads();
        }
        if (tid == 0) {
            unsigned int u = sh_prefix;
            thres_p[0] = (u & 0x80000000u) ? __uint_as_float(u ^ 0x80000000u) : __uint_as_float(~u);
        }
    } else if (blk <= 128) {
        const int id = (blk-1)*256 + tid;
        const unsigned long long below = (lane == 63) ? (~0ull >> 1) : ((1ull << lane) - 1ull);
        const bool is_tgt = (id < M_TGT);
        const int idx = is_tgt ? id : id - M_TGT;
        int4 c = is_tgt ? *(const int4*)&tcoords[idx*4] : *(const int4*)&coords[idx*4];
        const int b = c.x;
        float x = (float)c.y, y = (float)c.z, z = (float)c.w;
        float ss = x*x + y*y + z*z;
        if (is_tgt) {
            int key = ((c.x*64+c.y)*64+c.z)*64+c.w;
            atomicOr(&bmask[key>>5], 1u << (key&31));
        }
        const int cbase = is_tgt ? 0 : 4;
        #pragma unroll
        for (int bb = 0; bb < 4; ++bb) {
            unsigned long long m = __ballot(b == bb);
            if (m == 0ull) continue;
            int leader = __ffsll(m) - 1;
            int base = 0;
            if (lane == leader) base = atomicAdd(&cnt[cbase+bb], (int)__popcll(m));
            base = __shfl(base, leader);
            if (b == bb) {
                int r = base + (int)__popcll(m & below);
                if (r < CAP) {
                    if (is_tgt) tgt4[b*CAP+r] = make_float4(-2.f*x,-2.f*y,-2.f*z,ss);
                    else { pt4[b*CAP+r] = make_float4(x,y,z,ss); porig[b*CAP+r] = idx; }
                }
            }
        }
    }

    grid.sync();

    // ---------------- Phase D: NN ----------------
    {
        const int b  = blk >> 7;           // 4 batches x 128 point-groups
        const int pg = blk & 127;
        const int cntt = min(cnt[b], CAP);
        const int cntp = min(cnt[4+b], CAP);
        const int pidx = pg*64 + lane;
        const int w = __builtin_amdgcn_readfirstlane(tid >> 6);   // jslice per wave
        float4 P = pt4[b*CAP + pidx];      // in-bounds always; garbage unused under guard
        const int q = (cntt + 3) >> 2;
        int j0 = w*q, j1 = min(j0+q, cntt);
        const float4* tb = tgt4 + b*CAP;
        float m0 = INFF;
        int j = j0;
        for (; j+4 <= j1; j += 4) {        // uniform-address loads -> broadcast transactions
            float4 t0 = tb[j], t1 = tb[j+1], t2 = tb[j+2], t3 = tb[j+3];
            float d0 = fmaf(P.x,t0.x,t0.w); d0=fmaf(P.y,t0.y,d0); d0=fmaf(P.z,t0.z,d0);
            float d1 = fmaf(P.x,t1.x,t1.w); d1=fmaf(P.y,t1.y,d1); d1=fmaf(P.z,t1.z,d1);
            float d2 = fmaf(P.x,t2.x,t2.w); d2=fmaf(P.y,t2.y,d2); d2=fmaf(P.z,t2.z,d2);
            float d3 = fmaf(P.x,t3.x,t3.w); d3=fmaf(P.y,t3.y,d3); d3=fmaf(P.z,t3.z,d3);
            m0 = fminf(m0, fminf(fminf(d0,d1), fminf(d2,d3)));
        }
        for (; j < j1; ++j) {
            float4 t0 = tb[j];
            float d0 = fmaf(P.x,t0.x,t0.w); d0=fmaf(P.y,t0.y,d0); d0=fmaf(P.z,t0.z,d0);
            m0 = fminf(m0, d0);
        }
        if (pidx < cntp) partial[porig[b*CAP + pidx]*4 + w] = m0;
    }

    grid.sync();

    // ---------------- Phase E: epilogue, 32 rows/block ----------------
    {
        const int r0 = blk * 32;
        if (tid < 32) {
            const int i = r0 + tid;
            float p = out_pred[i];
            float thres = thres_p[0];
            int4 c = *(const int4*)&coords[i*4];
            float dmin = fminf(fminf(partial[i*4+0], partial[i*4+1]),
                               fminf(partial[i*4+2], partial[i*4+3]));
            float px = (float)c.y, py = (float)c.z, pz = (float)c.w;
            float pp = px*px + py*py + pz*pz;
            float dists = fmaxf(dmin + pp, 0.f);
            int key = ((c.x*64+c.y)*64+c.z)*64+c.w;
            bool kt = (bmask[key>>5] >> (key&31)) & 1u;
            bool keep0 = (p <= thres);
            bool pm = (p > DUB2), tm = (dists > DUB2);
            float loss = (pm && tm) ? p : ((!pm && tm) ? DUB2 : dists);
            bool kf = keep0 || kt;
            out_keep[i] = kf ? 1.f : 0.f;
            out_kt[i]  = kt ? 1.f : 0.f;
            out_loss[i] = loss;
            kscale[tid] = kf ? 1.f : 0.f;
        }
        __syncthreads();
        float4* fbase = (float4*)(out_fea + r0*64);
        #pragma unroll
        for (int qq = 0; qq < 2; ++qq) {
            int v = tid + qq*256;          // 32 rows x 16 float4 = 512
            float sc = kscale[v >> 4];
            float4 xv = fbase[v];
            xv.x*=sc; xv.y*=sc; xv.z*=sc; xv.w*=sc;
            fbase[v] = xv;
        }
    }
}

extern "C" void kernel_launch(void* const* d_in, const int* in_sizes, int n_in,
                              void* d_out, int out_size, void* d_ws, size_t ws_size,
                              hipStream_t stream) {
    const float* fea     = (const float*)d_in[0];
    const float* Wup     = (const float*)d_in[1];
    const float* Wcls    = (const float*)d_in[2];
    const int*   coords  = (const int*)d_in[3];
    const int*   tcoords = (const int*)d_in[4];

    float* out      = (float*)d_out;
    float* out_pred = out;
    float* out_fea  = out + N_PTS;
    float* out_keep = out + N_PTS + N_PTS * 64;
    float* out_kt   = out_keep + N_PTS;
    float* out_loss = out_kt + N_PTS;

    char* ws = (char*)d_ws;
    int*          cnt     = (int*)ws;                          // 64 B
    unsigned int* bmask   = (unsigned int*)(ws + 64);          // 128 KB -> 131136
    float*        thres   = (float*)(ws + 131136);             // 256 B  -> 131392
    float4*       tgt4    = (float4*)(ws + 131392);            // 512 KB -> 655680
    float4*       pt4     = (float4*)(ws + 655680);            // 512 KB -> 1179968
    int*          porig   = (int*)(ws + 1179968);              // 128 KB -> 1311040
    float*        partial = (float*)(ws + 1311040);            // 256 KB -> 1573184

    void* args[] = { (void*)&fea, (void*)&Wup, (void*)&Wcls, (void*)&coords,
                     (void*)&tcoords, (void*)&out_pred, (void*)&out_fea,
                     (void*)&out_keep, (void*)&out_kt, (void*)&out_loss,
                     (void*)&cnt, (void*)&bmask, (void*)&thres, (void*)&tgt4,
                     (void*)&pt4, (void*)&porig, (void*)&partial };
    hipLaunchCooperativeKernel((const void*)k_all, dim3(NBLK), dim3(256),
                               args, 0, stream);
}

// Round 11
// 35.075 us; speedup vs baseline: 9.5118x; 9.5118x over previous
//
#include <hip/hip_runtime.h>
#include <math.h>

#define N_PTS 16384
#define M_TGT 16384
#define TPN 8192
#define DUB2 4.0f
#define BMASK_WORDS (4*64*64*64/32)

__device__ __forceinline__ unsigned int mono_key(float f) {
    unsigned int u = __float_as_uint(f);
    return (u & 0x80000000u) ? ~u : (u | 0x80000000u);
}

// 33 integer offsets with dx^2+dy^2+dz^2 <= 4, grouped by d2 = 0,1,2,3,4.
__device__ const signed char NOFF[33][3] = {
    {0,0,0},
    {1,0,0},{-1,0,0},{0,1,0},{0,-1,0},{0,0,1},{0,0,-1},
    {1,1,0},{1,-1,0},{-1,1,0},{-1,-1,0},{1,0,1},{1,0,-1},{-1,0,1},{-1,0,-1},
    {0,1,1},{0,1,-1},{0,-1,1},{0,-1,-1},
    {1,1,1},{1,1,-1},{1,-1,1},{1,-1,-1},{-1,1,1},{-1,1,-1},{-1,-1,1},{-1,-1,-1},
    {2,0,0},{-2,0,0},{0,2,0},{0,-2,0},{0,0,2},{0,0,-2}
};

// K1: fea_up = relu(fea @ Wup); pred = fea_up @ Wcls. Also zeroes bmask
// (32 words/block x 1024 blocks) -- stream order guarantees completion
// before K2's atomicOr.
__global__ __launch_bounds__(256) void k_gemm(const float* __restrict__ fea,
        const float* __restrict__ Wup, const float* __restrict__ Wcls,
        float* __restrict__ out_pred, float* __restrict__ out_fea,
        unsigned int* __restrict__ bmask) {
    __shared__ float Ws[64 * 64];
    __shared__ float fs[16 * 68];
    const int tid = threadIdx.x;
    const int r0 = blockIdx.x * 16;

    if (tid < 32) bmask[blockIdx.x * 32 + tid] = 0u;

    for (int t = tid; t < 1024; t += 256)
        ((float4*)Ws)[t] = ((const float4*)Wup)[t];
    {
        float4 v = ((const float4*)(fea + r0 * 64))[tid];
        int r = tid >> 4, c = (tid & 15) * 4;
        fs[r*68 + c + 0] = v.x; fs[r*68 + c + 1] = v.y;
        fs[r*68 + c + 2] = v.z; fs[r*68 + c + 3] = v.w;
    }
    __syncthreads();

    const int cg = tid & 15;
    const int r  = tid >> 4;
    float a0 = 0.f, a1 = 0.f, a2 = 0.f, a3 = 0.f;
    const float* fr = fs + r * 68;
    #pragma unroll
    for (int k = 0; k < 64; ++k) {
        float f = fr[k];
        float4 w = *(const float4*)&Ws[k * 64 + cg * 4];
        a0 = fmaf(f, w.x, a0); a1 = fmaf(f, w.y, a1);
        a2 = fmaf(f, w.z, a2); a3 = fmaf(f, w.w, a3);
    }
    a0 = fmaxf(a0, 0.f); a1 = fmaxf(a1, 0.f);
    a2 = fmaxf(a2, 0.f); a3 = fmaxf(a3, 0.f);
    const int row = r0 + r;
    *(float4*)&out_fea[row * 64 + cg * 4] = make_float4(a0, a1, a2, a3);

    float4 wc = *(const float4*)&Wcls[cg * 4];
    float s = a0*wc.x + a1*wc.y + a2*wc.z + a3*wc.w;
    for (int off = 1; off < 16; off <<= 1) s += __shfl_xor(s, off, 16);
    if (cg == 0) out_pred[row] = s;
}

// K2: block 0 = exact radix-256 select of 8192nd smallest (keys in LDS,
// wave-private hists, parallel scan); blocks 1..16 = target bitmask build.
__global__ __launch_bounds__(1024) void k_selscat(const float* __restrict__ p,
        const int* __restrict__ tc, unsigned int* __restrict__ bmask,
        float* __restrict__ thres_out) {
    __shared__ unsigned int keys[N_PTS];        // 64 KB
    __shared__ unsigned int whist[16][256];     // 16 KB
    __shared__ unsigned int hist[256];
    __shared__ unsigned int scanb[256];
    __shared__ unsigned int sh_prefix, sh_rank;
    const int tid = threadIdx.x;

    if (blockIdx.x != 0) {                      // bitmask build
        const int id = (blockIdx.x - 1) * 1024 + tid;
        int4 c = *(const int4*)&tc[id * 4];
        int key = ((c.x * 64 + c.y) * 64 + c.z) * 64 + c.w;
        atomicOr(&bmask[key >> 5], 1u << (key & 31));
        return;
    }

    const int w = tid >> 6;
    for (int i = tid; i < N_PTS / 4; i += 1024) {
        float4 v = ((const float4*)p)[i];
        keys[i*4 + 0] = mono_key(v.x);
        keys[i*4 + 1] = mono_key(v.y);
        keys[i*4 + 2] = mono_key(v.z);
        keys[i*4 + 3] = mono_key(v.w);
    }
    if (tid == 0) { sh_prefix = 0u; sh_rank = TPN - 1; }
    __syncthreads();

    for (int pass = 0; pass < 4; ++pass) {
        const int shift = 24 - pass * 8;
        const unsigned int prefix = sh_prefix;
        const unsigned int rank = sh_rank;
        for (int t = tid; t < 16 * 256; t += 1024) ((unsigned int*)whist)[t] = 0u;
        __syncthreads();
        for (int i = tid; i < N_PTS; i += 1024) {
            unsigned int u = keys[i];
            bool match = (pass == 0) || ((u >> (shift + 8)) == prefix);
            if (match) atomicAdd(&whist[w][(u >> shift) & 255u], 1u);
        }
        __syncthreads();
        if (tid < 256) {
            unsigned int s = 0u;
            #pragma unroll
            for (int ww = 0; ww < 16; ++ww) s += whist[ww][tid];
            hist[tid] = s;
            scanb[tid] = s;
        }
        __syncthreads();
        for (int d = 1; d < 256; d <<= 1) {
            unsigned int v = 0u;
            if (tid < 256 && tid >= d) v = scanb[tid - d];
            __syncthreads();
            if (tid < 256) scanb[tid] += v;
            __syncthreads();
        }
        if (tid < 256) {
            unsigned int hi = scanb[tid];
            unsigned int lo = hi - hist[tid];
            if (rank >= lo && rank < hi) {
                sh_prefix = (prefix << 8) | (unsigned int)tid;
                sh_rank = rank - lo;
            }
        }
        __syncthreads();
    }
    if (tid == 0) {
        unsigned int u = sh_prefix;
        thres_out[0] = (u & 0x80000000u) ? __uint_as_float(u ^ 0x80000000u)
                                         : __uint_as_float(~u);
    }
}

// K3: epilogue with bitmask-probe NN. dists is only exposed when <=4, and
// coords are integers, so probing the 33 neighbor cells with d2<=4 in
// increasing-d2 groups gives the EXACT reference output in every branch
// (not-found => dists>4 => output is p or 4.0, never dists). 64 rows/block.
__global__ __launch_bounds__(256) void k_final(const int* __restrict__ coords,
        const unsigned int* __restrict__ bmask, const float* __restrict__ thres_p,
        const float* __restrict__ out_pred, float* __restrict__ out_fea,
        float* __restrict__ out_keep, float* __restrict__ out_kt,
        float* __restrict__ out_loss) {
    __shared__ float kscale[64];
    const int tid = threadIdx.x;
    const int r0 = blockIdx.x * 64;
    if (tid < 64) {
        const int i = r0 + tid;
        float p = out_pred[i];
        float thres = thres_p[0];
        int4 c = *(const int4*)&coords[i * 4];
        const int b = c.x, x = c.y, y = c.z, z = c.w;
        int key0 = ((b * 64 + x) * 64 + y) * 64 + z;
        bool kt = (bmask[key0 >> 5] >> (key0 & 31)) & 1u;
        float dists;
        if (kt) {
            dists = 0.f;
        } else {
            dists = 5.f;                     // sentinel > DUB2: "not found"
            int t = 1;
            #pragma unroll
            for (int g = 1; g <= 4; ++g) {
                const int gend = (g == 1) ? 7 : (g == 2) ? 19 : (g == 3) ? 27 : 33;
                bool hit = false;
                for (; t < gend; ++t) {
                    int ox = x + NOFF[t][0], oy = y + NOFF[t][1], oz = z + NOFF[t][2];
                    if (((unsigned)ox | (unsigned)oy | (unsigned)oz) < 64u) {
                        int key = ((b * 64 + ox) * 64 + oy) * 64 + oz;
                        hit |= (bmask[key >> 5] >> (key & 31)) & 1u;
                    }
                }
                if (hit) { dists = (float)g; break; }
            }
        }
        bool keep0 = (p <= thres);
        bool pm = (p > DUB2), tm = (dists > DUB2);
        float loss = (pm && tm) ? p : ((!pm && tm) ? DUB2 : dists);
        bool kf = keep0 || kt;
        out_keep[i] = kf ? 1.f : 0.f;
        out_kt[i]  = kt ? 1.f : 0.f;
        out_loss[i] = loss;
        kscale[tid] = kf ? 1.f : 0.f;
    }
    __syncthreads();
    float4* fbase = (float4*)(out_fea + r0 * 64);
    #pragma unroll
    for (int q = 0; q < 4; ++q) {
        int v = tid + q * 256;               // 64 rows x 16 float4 = 1024
        float sc = kscale[v >> 4];
        float4 xv = fbase[v];
        xv.x *= sc; xv.y *= sc; xv.z *= sc; xv.w *= sc;
        fbase[v] = xv;
    }
}

extern "C" void kernel_launch(void* const* d_in, const int* in_sizes, int n_in,
                              void* d_out, int out_size, void* d_ws, size_t ws_size,
                              hipStream_t stream) {
    const float* fea     = (const float*)d_in[0];
    const float* Wup     = (const float*)d_in[1];
    const float* Wcls    = (const float*)d_in[2];
    const int*   coords  = (const int*)d_in[3];
    const int*   tcoords = (const int*)d_in[4];

    float* out      = (float*)d_out;
    float* out_pred = out;
    float* out_fea  = out + N_PTS;
    float* out_keep = out + N_PTS + N_PTS * 64;
    float* out_kt   = out_keep + N_PTS;
    float* out_loss = out_kt + N_PTS;

    char* ws = (char*)d_ws;
    unsigned int* bmask   = (unsigned int*)(ws + 64);          // 128 KB -> 131136
    float*        thres   = (float*)(ws + 131136);             // 4 B

    k_gemm   <<<N_PTS / 16, 256, 0, stream>>>(fea, Wup, Wcls, out_pred, out_fea, bmask);
    k_selscat<<<1 + M_TGT / 1024, 1024, 0, stream>>>(out_pred, tcoords, bmask, thres);
    k_final  <<<N_PTS / 64, 256, 0, stream>>>(coords, bmask, thres,
                                              out_pred, out_fea, out_keep, out_kt, out_loss);
}